// Round 5
// baseline (215.407 us; speedup 1.0000x reference)
//
#include <hip/hip_runtime.h>
#include <hip/hip_bf16.h>

#define B_  32
#define HW_ 4096
#define C_  256
#define S_LDS 40   // LDS row stride in ushorts (80B): b128 r/w ~2-way banks (measured free)

using bf16x8 = __attribute__((ext_vector_type(8))) short;
using f32x4  = __attribute__((ext_vector_type(4))) float;

__device__ __forceinline__ ushort f2bf_rn(float x) {
    uint u = __builtin_bit_cast(uint, x);
    u += 0x7FFFu + ((u >> 16) & 1u);
    return (ushort)(u >> 16);
}
__device__ __forceinline__ uint pk_bf2(float a, float b) {   // RN pack (K2 only)
    return ((uint)f2bf_rn(b) << 16) | (uint)f2bf_rn(a);
}
// 1-instr RTZ pack of two floats' top-16 bits: {bf16_rtz(x1), bf16_rtz(x0)}
__device__ __forceinline__ uint pk_rtz(float x0, float x1) {
    return __builtin_amdgcn_perm(__builtin_bit_cast(uint, x1),
                                 __builtin_bit_cast(uint, x0), 0x07060302u);
}
// RTZ split: x = hi + lo, hi = truncate-to-bf16, |lo| <= 2^-8|x|
__device__ __forceinline__ void split2_rtz(float x0, float x1, uint& hi2, uint& lo2) {
    uint u0 = __builtin_bit_cast(uint, x0), u1 = __builtin_bit_cast(uint, x1);
    hi2 = __builtin_amdgcn_perm(u1, u0, 0x07060302u);
    float h0 = __builtin_bit_cast(float, u0 & 0xFFFF0000u);
    float h1 = __builtin_bit_cast(float, u1 & 0xFFFF0000u);
    lo2 = pk_rtz(x0 - h0, x1 - h1);
}

// ---------------------------------------------------------------------------
// K1: scores[b,q,k] = sum_hw Q[b,hw,q]*K[b,hw,k] via 3-term bf16 RTZ split.
// Tile 128(q) x 128(k), split-K=4, 512-thread blocks (8 waves, 2x4 wave grid,
// each wave 64q x 32k). Register-double-buffered staging; atomicAdd epilogue.
// grid 512 = b(32) * tm(2) * tn(2) * s(4).
// ---------------------------------------------------------------------------
__global__ __launch_bounds__(512, 4) void scores_kernel(const float* __restrict__ qg,
                                                        const float* __restrict__ kg,
                                                        float* __restrict__ scores) {
    int x  = blockIdx.x;
    int s  = x & 3;
    int tn = (x >> 2) & 1;
    int tm = (x >> 3) & 1;
    int b  = x >> 4;

    __shared__ __align__(16) ushort Qhi[128 * S_LDS], Qlo[128 * S_LDS];
    __shared__ __align__(16) ushort Khi[128 * S_LDS], Klo[128 * S_LDS];

    int tid = threadIdx.x, lane = tid & 63, w = tid >> 6;
    int m0 = (w >> 2) * 64;     // 2 m-groups of waves
    int n0 = (w & 3) * 32;      // 4 n-groups
    int g = lane >> 4, r16 = lane & 15;

    int cc = tid & 127;          // staging channel (same index for Q and K)
    int hh = (tid >> 7) * 8;     // hw offset 0/8/16/24 (8 values per thread)

    const float* qcol = qg + (size_t)b * HW_ * C_ + tm * 128 + cc;
    const float* kcol = kg + (size_t)b * HW_ * C_ + tn * 128 + cc;

    f32x4 acc[4][2];
#pragma unroll
    for (int i = 0; i < 4; ++i)
#pragma unroll
        for (int j = 0; j < 2; ++j) acc[i][j] = (f32x4){0.f, 0.f, 0.f, 0.f};

#define LOAD_QK(qr, kr, itv) {                                                 \
        int hw0 = s * 1024 + (itv) * 32 + hh;                                  \
        const float* qp = qcol + (size_t)hw0 * C_;                             \
        const float* kp = kcol + (size_t)hw0 * C_;                             \
        _Pragma("unroll")                                                      \
        for (int j = 0; j < 8; ++j) qr[j] = qp[(size_t)j * C_];                \
        _Pragma("unroll")                                                      \
        for (int j = 0; j < 8; ++j) kr[j] = kp[(size_t)j * C_];                \
    }

#define CONVERT_STORE(qr, kr) {                                                \
        uint qh[4], ql[4], kh[4], kl[4];                                       \
        _Pragma("unroll")                                                      \
        for (int p = 0; p < 4; ++p) {                                          \
            split2_rtz(qr[2*p], qr[2*p+1], qh[p], ql[p]);                      \
            split2_rtz(kr[2*p], kr[2*p+1], kh[p], kl[p]);                      \
        }                                                                      \
        int base_ = cc * S_LDS + hh;                                           \
        *reinterpret_cast<uint4*>(&Qhi[base_]) = make_uint4(qh[0], qh[1], qh[2], qh[3]); \
        *reinterpret_cast<uint4*>(&Qlo[base_]) = make_uint4(ql[0], ql[1], ql[2], ql[3]); \
        *reinterpret_cast<uint4*>(&Khi[base_]) = make_uint4(kh[0], kh[1], kh[2], kh[3]); \
        *reinterpret_cast<uint4*>(&Klo[base_]) = make_uint4(kl[0], kl[1], kl[2], kl[3]); \
    }

#define MFMA_PHASE() {                                                         \
        bf16x8 ahi[4], alo[4];                                                 \
        _Pragma("unroll")                                                      \
        for (int mi = 0; mi < 4; ++mi) {                                       \
            int off = (m0 + mi * 16 + r16) * S_LDS + g * 8;                    \
            ahi[mi] = *reinterpret_cast<const bf16x8*>(&Qhi[off]);             \
            alo[mi] = *reinterpret_cast<const bf16x8*>(&Qlo[off]);             \
        }                                                                      \
        _Pragma("unroll")                                                      \
        for (int ni = 0; ni < 2; ++ni) {                                       \
            int off = (n0 + ni * 16 + r16) * S_LDS + g * 8;                    \
            bf16x8 bhi = *reinterpret_cast<const bf16x8*>(&Khi[off]);          \
            bf16x8 blo = *reinterpret_cast<const bf16x8*>(&Klo[off]);          \
            _Pragma("unroll")                                                  \
            for (int mi = 0; mi < 4; ++mi) {                                   \
                acc[mi][ni] = __builtin_amdgcn_mfma_f32_16x16x32_bf16(ahi[mi], bhi, acc[mi][ni], 0, 0, 0); \
                acc[mi][ni] = __builtin_amdgcn_mfma_f32_16x16x32_bf16(ahi[mi], blo, acc[mi][ni], 0, 0, 0); \
                acc[mi][ni] = __builtin_amdgcn_mfma_f32_16x16x32_bf16(alo[mi], bhi, acc[mi][ni], 0, 0, 0); \
            }                                                                  \
        }                                                                      \
    }

#define STEP(qc, kc, qn, kn, itv, doload) {                                    \
        if (doload) LOAD_QK(qn, kn, (itv) + 1);                                \
        __syncthreads();                                                       \
        CONVERT_STORE(qc, kc);                                                 \
        __syncthreads();                                                       \
        MFMA_PHASE();                                                          \
    }

    float qa[8], ka[8], qb[8], kb[8];
    LOAD_QK(qa, ka, 0);
    for (int p = 0; p < 16; ++p) {
        STEP(qa, ka, qb, kb, 2 * p, true);
        STEP(qb, kb, qa, ka, 2 * p + 1, p < 15);
    }

#pragma unroll
    for (int mi = 0; mi < 4; ++mi)
#pragma unroll
        for (int ni = 0; ni < 2; ++ni)
#pragma unroll
            for (int r = 0; r < 4; ++r) {
                int qrow = tm * 128 + m0 + mi * 16 + g * 4 + r;
                int kc   = tn * 128 + n0 + ni * 16 + r16;
                atomicAdd(&scores[((size_t)b * 256 + qrow) * 256 + kc], acc[mi][ni][r]);
            }
#undef STEP
#undef MFMA_PHASE
#undef CONVERT_STORE
#undef LOAD_QK
}

// ---------------------------------------------------------------------------
// K2: row softmax over k (256), one wave per row; attn stored as bf16 (RN).
// ---------------------------------------------------------------------------
__global__ __launch_bounds__(256) void softmax_kernel(const float* __restrict__ scores,
                                                      ushort* __restrict__ attn) {
    int wid  = blockIdx.x * 4 + (threadIdx.x >> 6);
    int lane = threadIdx.x & 63;
    const float4 v = *reinterpret_cast<const float4*>(scores + (size_t)wid * 256 + lane * 4);
    float m = fmaxf(fmaxf(v.x, v.y), fmaxf(v.z, v.w));
#pragma unroll
    for (int off = 32; off; off >>= 1) m = fmaxf(m, __shfl_xor(m, off, 64));
    float e0 = __expf(v.x - m), e1 = __expf(v.y - m), e2 = __expf(v.z - m), e3 = __expf(v.w - m);
    float ssum = e0 + e1 + e2 + e3;
#pragma unroll
    for (int off = 32; off; off >>= 1) ssum += __shfl_xor(ssum, off, 64);
    float inv = 1.0f / ssum;
    uint2 o;
    o.x = pk_bf2(e0 * inv, e1 * inv);
    o.y = pk_bf2(e2 * inv, e3 * inv);
    *reinterpret_cast<uint2*>(attn + (size_t)wid * 256 + lane * 4) = o;
}

// ---------------------------------------------------------------------------
// K3: out[b,q,hw] = sum_k attn[b,q,k] * V[b,hw,k].  M=256 x N=64 tile, K=256
// in 8 steps of 32; depth-1 register double-buffer (attn + V) hides HBM
// latency under pack+MFMA. V packed fp32->bf16 via 1-instr v_perm RTZ.
// ---------------------------------------------------------------------------
__global__ __launch_bounds__(256, 3) void pv_kernel(const ushort* __restrict__ attn,
                                                    const float* __restrict__ vg,
                                                    float* __restrict__ out) {
    int b   = blockIdx.x >> 6;
    int hw0 = (blockIdx.x & 63) * 64;
    int tid = threadIdx.x, lane = tid & 63, w = tid >> 6;
    int m0  = w * 64;
    int g   = lane >> 4, r16 = lane & 15;

    const ushort* abase = attn + (size_t)b * 256 * 256 + g * 8;
    const float*  vbase = vg + ((size_t)(b * HW_ + hw0 + r16)) * C_ + g * 8;

    f32x4 acc[4][4];
#pragma unroll
    for (int i = 0; i < 4; ++i)
#pragma unroll
        for (int j = 0; j < 4; ++j) acc[i][j] = (f32x4){0.f, 0.f, 0.f, 0.f};

#define K3_LOAD(abuf, vbuf, ksv) {                                             \
        int k0_ = (ksv) * 32;                                                  \
        _Pragma("unroll")                                                      \
        for (int mi = 0; mi < 4; ++mi)                                         \
            abuf[mi] = *reinterpret_cast<const bf16x8*>(abase + (size_t)(m0 + mi * 16 + r16) * 256 + k0_); \
        _Pragma("unroll")                                                      \
        for (int ni = 0; ni < 4; ++ni) {                                       \
            const float* vp_ = vbase + (size_t)ni * 16 * C_ + k0_;             \
            vbuf[ni][0] = *reinterpret_cast<const float4*>(vp_);               \
            vbuf[ni][1] = *reinterpret_cast<const float4*>(vp_ + 4);           \
        }                                                                      \
    }

#define K3_COMPUTE(abuf, vbuf) {                                               \
        _Pragma("unroll")                                                      \
        for (int ni = 0; ni < 4; ++ni) {                                       \
            bf16x8 bf;                                                         \
            uint* bu = reinterpret_cast<uint*>(&bf);                           \
            bu[0] = pk_rtz(vbuf[ni][0].x, vbuf[ni][0].y);                      \
            bu[1] = pk_rtz(vbuf[ni][0].z, vbuf[ni][0].w);                      \
            bu[2] = pk_rtz(vbuf[ni][1].x, vbuf[ni][1].y);                      \
            bu[3] = pk_rtz(vbuf[ni][1].z, vbuf[ni][1].w);                      \
            _Pragma("unroll")                                                  \
            for (int mi = 0; mi < 4; ++mi)                                     \
                acc[mi][ni] = __builtin_amdgcn_mfma_f32_16x16x32_bf16(abuf[mi], bf, acc[mi][ni], 0, 0, 0); \
        }                                                                      \
    }

    bf16x8 aA[4], aB[4];
    float4 vA[4][2], vB[4][2];
    K3_LOAD(aA, vA, 0);
#pragma unroll
    for (int p = 0; p < 4; ++p) {
        K3_LOAD(aB, vB, 2 * p + 1);
        K3_COMPUTE(aA, vA);
        if (p < 3) K3_LOAD(aA, vA, 2 * p + 2);
        K3_COMPUTE(aB, vB);
    }
#undef K3_LOAD
#undef K3_COMPUTE

#pragma unroll
    for (int mi = 0; mi < 4; ++mi)
#pragma unroll
        for (int ni = 0; ni < 4; ++ni)
#pragma unroll
            for (int r = 0; r < 4; ++r) {
                int qrow = m0 + mi * 16 + g * 4 + r;
                int hw   = hw0 + ni * 16 + r16;
                out[((size_t)b * 256 + qrow) * 4096 + hw] = acc[mi][ni][r];
            }
}

extern "C" void kernel_launch(void* const* d_in, const int* in_sizes, int n_in,
                              void* d_out, int out_size, void* d_ws, size_t ws_size,
                              hipStream_t stream) {
    const float* q = (const float*)d_in[0];
    const float* k = (const float*)d_in[1];
    const float* v = (const float*)d_in[2];
    float* out = (float*)d_out;

    float*  scores = (float*)d_ws;
    ushort* attn   = (ushort*)((char*)d_ws + (size_t)B_ * 256 * 256 * 4);

    (void)hipMemsetAsync(d_ws, 0, (size_t)B_ * 256 * 256 * 4, stream);
    scores_kernel<<<512, 512, 0, stream>>>(q, k, scores);
    softmax_kernel<<<2048, 256, 0, stream>>>(scores, attn);
    pv_kernel<<<2048, 256, 0, stream>>>(attn, v, out);
}

// Round 6
// 185.877 us; speedup vs baseline: 1.1589x; 1.1589x over previous
//
#include <hip/hip_runtime.h>
#include <hip/hip_bf16.h>

#define B_  32
#define HW_ 4096
#define C_  256

using bf16x8 = __attribute__((ext_vector_type(8))) short;
using f32x4  = __attribute__((ext_vector_type(4))) float;
using u32x4  = __attribute__((ext_vector_type(4))) uint;

__device__ __forceinline__ ushort f2bf_rn(float x) {
    uint u = __builtin_bit_cast(uint, x);
    u += 0x7FFFu + ((u >> 16) & 1u);
    return (ushort)(u >> 16);
}
__device__ __forceinline__ uint pk_bf2(float a, float b) {   // RN pack (K2 only)
    return ((uint)f2bf_rn(b) << 16) | (uint)f2bf_rn(a);
}
// 1-instr RTZ pack of two floats' top-16 bits: {bf16_rtz(x1), bf16_rtz(x0)}
__device__ __forceinline__ uint pk_rtz(float x0, float x1) {
    return __builtin_amdgcn_perm(__builtin_bit_cast(uint, x1),
                                 __builtin_bit_cast(uint, x0), 0x07060302u);
}
// RTZ split: x = hi + lo, hi = truncate-to-bf16, |lo| <= 2^-8|x|
__device__ __forceinline__ void split2_rtz(float x0, float x1, uint& hi2, uint& lo2) {
    uint u0 = __builtin_bit_cast(uint, x0), u1 = __builtin_bit_cast(uint, x1);
    hi2 = __builtin_amdgcn_perm(u1, u0, 0x07060302u);
    float h0 = __builtin_bit_cast(float, u0 & 0xFFFF0000u);
    float h1 = __builtin_bit_cast(float, u1 & 0xFFFF0000u);
    lo2 = pk_rtz(x0 - h0, x1 - h1);
}
// build fragments (hi,lo) from 8 contiguous fp32
__device__ __forceinline__ void frag_from_f32(const f32x4& f0, const f32x4& f1,
                                              bf16x8& hi, bf16x8& lo) {
    uint h0, l0, h1, l1, h2, l2, h3, l3;
    split2_rtz(f0[0], f0[1], h0, l0);
    split2_rtz(f0[2], f0[3], h1, l1);
    split2_rtz(f1[0], f1[1], h2, l2);
    split2_rtz(f1[2], f1[3], h3, l3);
    hi = __builtin_bit_cast(bf16x8, (u32x4){h0, h1, h2, h3});
    lo = __builtin_bit_cast(bf16x8, (u32x4){l0, l1, l2, l3});
}

// ---------------------------------------------------------------------------
// K1: scores[b,q,k] = sum_hw Q[b,hw,q]*K[b,hw,k] via 3-term bf16 RTZ split.
// Tile 128(q) x 128(k), split-K=8, 512-thread blocks (8 waves, 2x4 wave grid).
// LDS holds RAW fp32 tiles [128 ch][32 hw] with 16B-slot XOR swizzle
// (slot ^= row&7, row stride 32 floats): b128 writes/reads aligned and
// bank-optimal. bf16 split happens on read, co-issuing with MFMA.
// grid 1024 = b(32) * tm(2) * tn(2) * s(8) -> 4 blocks/CU.
// ---------------------------------------------------------------------------
__global__ __launch_bounds__(512, 4) void scores_kernel(const float* __restrict__ qg,
                                                        const float* __restrict__ kg,
                                                        float* __restrict__ scores) {
    int x  = blockIdx.x;
    int s  = x & 7;
    int tn = (x >> 3) & 1;
    int tm = (x >> 4) & 1;
    int b  = x >> 5;

    __shared__ __align__(16) float Qt[128 * 32], Kt[128 * 32];

    int tid = threadIdx.x, lane = tid & 63, w = tid >> 6;
    int m0 = (w >> 2) * 64;     // 2 m-groups of waves
    int n0 = (w & 3) * 32;      // 4 n-groups
    int g = lane >> 4, r16 = lane & 15;

    int cc = tid & 127;          // staging channel (row) owned by this thread
    int s0 = (tid >> 7) * 2;     // logical 16B-slot base; hw offset = s0*4
    int hh = s0 * 4;             // hw offset 0/8/16/24

    // physical (swizzled) write indices, float units
    int wi0 = cc * 32 + ((s0 ^ (cc & 7)) * 4);
    int wi1 = cc * 32 + (((s0 + 1) ^ (cc & 7)) * 4);

    const float* qcol = qg + (size_t)b * HW_ * C_ + tm * 128 + cc;
    const float* kcol = kg + (size_t)b * HW_ * C_ + tn * 128 + cc;

    f32x4 acc[4][2];
#pragma unroll
    for (int i = 0; i < 4; ++i)
#pragma unroll
        for (int j = 0; j < 2; ++j) acc[i][j] = (f32x4){0.f, 0.f, 0.f, 0.f};

#define LOAD_QK(qr, kr, itv) {                                                 \
        int hw0 = s * 512 + (itv) * 32 + hh;                                   \
        const float* qp = qcol + (size_t)hw0 * C_;                             \
        const float* kp = kcol + (size_t)hw0 * C_;                             \
        _Pragma("unroll")                                                      \
        for (int j = 0; j < 8; ++j) qr[j] = qp[(size_t)j * C_];                \
        _Pragma("unroll")                                                      \
        for (int j = 0; j < 8; ++j) kr[j] = kp[(size_t)j * C_];                \
    }

#define STORE_RAW(qr, kr) {                                                    \
        *reinterpret_cast<f32x4*>(&Qt[wi0]) = (f32x4){qr[0], qr[1], qr[2], qr[3]}; \
        *reinterpret_cast<f32x4*>(&Qt[wi1]) = (f32x4){qr[4], qr[5], qr[6], qr[7]}; \
        *reinterpret_cast<f32x4*>(&Kt[wi0]) = (f32x4){kr[0], kr[1], kr[2], kr[3]}; \
        *reinterpret_cast<f32x4*>(&Kt[wi1]) = (f32x4){kr[4], kr[5], kr[6], kr[7]}; \
    }

#define MFMA_PHASE() {                                                         \
        bf16x8 ahi[4], alo[4];                                                 \
        _Pragma("unroll")                                                      \
        for (int mi = 0; mi < 4; ++mi) {                                       \
            int row = m0 + mi * 16 + r16, key = row & 7;                       \
            f32x4 f0 = *reinterpret_cast<const f32x4*>(&Qt[row * 32 + (((2*g)   ^ key) * 4)]); \
            f32x4 f1 = *reinterpret_cast<const f32x4*>(&Qt[row * 32 + (((2*g+1) ^ key) * 4)]); \
            frag_from_f32(f0, f1, ahi[mi], alo[mi]);                           \
        }                                                                      \
        _Pragma("unroll")                                                      \
        for (int ni = 0; ni < 2; ++ni) {                                       \
            int row = n0 + ni * 16 + r16, key = row & 7;                       \
            f32x4 f0 = *reinterpret_cast<const f32x4*>(&Kt[row * 32 + (((2*g)   ^ key) * 4)]); \
            f32x4 f1 = *reinterpret_cast<const f32x4*>(&Kt[row * 32 + (((2*g+1) ^ key) * 4)]); \
            bf16x8 bhi, blo;                                                   \
            frag_from_f32(f0, f1, bhi, blo);                                   \
            _Pragma("unroll")                                                  \
            for (int mi = 0; mi < 4; ++mi) {                                   \
                acc[mi][ni] = __builtin_amdgcn_mfma_f32_16x16x32_bf16(ahi[mi], bhi, acc[mi][ni], 0, 0, 0); \
                acc[mi][ni] = __builtin_amdgcn_mfma_f32_16x16x32_bf16(ahi[mi], blo, acc[mi][ni], 0, 0, 0); \
                acc[mi][ni] = __builtin_amdgcn_mfma_f32_16x16x32_bf16(alo[mi], bhi, acc[mi][ni], 0, 0, 0); \
            }                                                                  \
        }                                                                      \
    }

#define STEP(qc, kc, qn, kn, itv, doload) {                                    \
        if (doload) LOAD_QK(qn, kn, (itv) + 1);                                \
        __syncthreads();                                                       \
        STORE_RAW(qc, kc);                                                     \
        __syncthreads();                                                       \
        MFMA_PHASE();                                                          \
    }

    float qa[8], ka[8], qb[8], kb[8];
    LOAD_QK(qa, ka, 0);
    for (int p = 0; p < 8; ++p) {
        STEP(qa, ka, qb, kb, 2 * p, true);       // prefetch iter 2p+1 (<=15)
        STEP(qb, kb, qa, ka, 2 * p + 1, p < 7);  // prefetch iter 2p+2 (<=14)
    }

    // epilogue: C/D layout col=lane&15, row=(lane>>4)*4+reg (m89-verified)
#pragma unroll
    for (int mi = 0; mi < 4; ++mi)
#pragma unroll
        for (int ni = 0; ni < 2; ++ni)
#pragma unroll
            for (int r = 0; r < 4; ++r) {
                int qrow = tm * 128 + m0 + mi * 16 + g * 4 + r;
                int kc   = tn * 128 + n0 + ni * 16 + r16;
                atomicAdd(&scores[((size_t)b * 256 + qrow) * 256 + kc], acc[mi][ni][r]);
            }
#undef STEP
#undef MFMA_PHASE
#undef STORE_RAW
#undef LOAD_QK
}

// ---------------------------------------------------------------------------
// K2: row softmax over k (256), one wave per row; attn stored as bf16 (RN).
// ---------------------------------------------------------------------------
__global__ __launch_bounds__(256) void softmax_kernel(const float* __restrict__ scores,
                                                      ushort* __restrict__ attn) {
    int wid  = blockIdx.x * 4 + (threadIdx.x >> 6);
    int lane = threadIdx.x & 63;
    const float4 v = *reinterpret_cast<const float4*>(scores + (size_t)wid * 256 + lane * 4);
    float m = fmaxf(fmaxf(v.x, v.y), fmaxf(v.z, v.w));
#pragma unroll
    for (int off = 32; off; off >>= 1) m = fmaxf(m, __shfl_xor(m, off, 64));
    float e0 = __expf(v.x - m), e1 = __expf(v.y - m), e2 = __expf(v.z - m), e3 = __expf(v.w - m);
    float ssum = e0 + e1 + e2 + e3;
#pragma unroll
    for (int off = 32; off; off >>= 1) ssum += __shfl_xor(ssum, off, 64);
    float inv = 1.0f / ssum;
    uint2 o;
    o.x = pk_bf2(e0 * inv, e1 * inv);
    o.y = pk_bf2(e2 * inv, e3 * inv);
    *reinterpret_cast<uint2*>(attn + (size_t)wid * 256 + lane * 4) = o;
}

// ---------------------------------------------------------------------------
// K3: out[b,q,hw] = sum_k attn[b,q,k] * V[b,hw,k].  M=256 x N=64 tile, K=256
// in 8 steps of 32. V tile staged ONCE per block into LDS (fp32, XOR-swizzled
// 16B slots), double-buffered with T14 async-stage: issue ks+1 loads ->
// compute ks from LDS -> write ks+1 -> barrier. Waves read shared V from LDS.
// grid 2048 = b(32) * hw-tile(64); block 256 (4 waves, each 64q x 64hw).
// ---------------------------------------------------------------------------
__global__ __launch_bounds__(256, 4) void pv_kernel(const ushort* __restrict__ attn,
                                                    const float* __restrict__ vg,
                                                    float* __restrict__ out) {
    int b   = blockIdx.x >> 6;
    int hw0 = (blockIdx.x & 63) * 64;
    int tid = threadIdx.x, lane = tid & 63, w = tid >> 6;
    int m0  = w * 64;
    int g   = lane >> 4, r16 = lane & 15;

    __shared__ __align__(16) float Vt[2 * 64 * 32];   // [buf][hw 64][k 32], swizzled

    // staging: thread owns hw-row srow, logical k-slots {2*(tid&3), +1}
    int srow = tid >> 2;
    int sslot = (tid & 3) * 2;
    int wi0 = srow * 32 + ((sslot ^ (srow & 7)) * 4);
    int wi1 = srow * 32 + (((sslot + 1) ^ (srow & 7)) * 4);
    const float* vstage = vg + ((size_t)(b * HW_ + hw0 + srow)) * C_ + sslot * 4;

    const ushort* abase = attn + (size_t)b * 256 * 256 + g * 8;

    f32x4 acc[4][4];
#pragma unroll
    for (int i = 0; i < 4; ++i)
#pragma unroll
        for (int j = 0; j < 4; ++j) acc[i][j] = (f32x4){0.f, 0.f, 0.f, 0.f};

    // prologue: stage ks=0 into buf0
    {
        f32x4 p0 = *reinterpret_cast<const f32x4*>(vstage);
        f32x4 p1 = *reinterpret_cast<const f32x4*>(vstage + 4);
        *reinterpret_cast<f32x4*>(&Vt[wi0]) = p0;
        *reinterpret_cast<f32x4*>(&Vt[wi1]) = p1;
    }
    __syncthreads();

    for (int p = 0; p < 8; ++p) {
        float* rbuf = &Vt[(p & 1) * 64 * 32];
        float* wbuf = &Vt[((p + 1) & 1) * 64 * 32];

        // issue next tile's global loads early (T14: hide HBM under compute)
        f32x4 n0v, n1v;
        if (p < 7) {
            n0v = *reinterpret_cast<const f32x4*>(vstage + (p + 1) * 32);
            n1v = *reinterpret_cast<const f32x4*>(vstage + (p + 1) * 32 + 4);
        }

        int k0 = p * 32;
        bf16x8 a[4];
#pragma unroll
        for (int mi = 0; mi < 4; ++mi)
            a[mi] = *reinterpret_cast<const bf16x8*>(abase + (size_t)(m0 + mi * 16 + r16) * 256 + k0);

#pragma unroll
        for (int ni = 0; ni < 4; ++ni) {
            int row = ni * 16 + r16, key = row & 7;
            f32x4 f0 = *reinterpret_cast<const f32x4*>(&rbuf[row * 32 + (((2 * g)     ^ key) * 4)]);
            f32x4 f1 = *reinterpret_cast<const f32x4*>(&rbuf[row * 32 + (((2 * g + 1) ^ key) * 4)]);
            bf16x8 bf = __builtin_bit_cast(bf16x8, (u32x4){
                pk_rtz(f0[0], f0[1]), pk_rtz(f0[2], f0[3]),
                pk_rtz(f1[0], f1[1]), pk_rtz(f1[2], f1[3])});
#pragma unroll
            for (int mi = 0; mi < 4; ++mi)
                acc[mi][ni] = __builtin_amdgcn_mfma_f32_16x16x32_bf16(a[mi], bf, acc[mi][ni], 0, 0, 0);
        }

        if (p < 7) {
            *reinterpret_cast<f32x4*>(&wbuf[wi0]) = n0v;
            *reinterpret_cast<f32x4*>(&wbuf[wi1]) = n1v;
            __syncthreads();
        }
    }

#pragma unroll
    for (int mi = 0; mi < 4; ++mi)
#pragma unroll
        for (int ni = 0; ni < 4; ++ni)
#pragma unroll
            for (int r = 0; r < 4; ++r) {
                int qrow = m0 + mi * 16 + g * 4 + r;
                int hw   = hw0 + ni * 16 + r16;
                out[((size_t)b * 256 + qrow) * 4096 + hw] = acc[mi][ni][r];
            }
}

extern "C" void kernel_launch(void* const* d_in, const int* in_sizes, int n_in,
                              void* d_out, int out_size, void* d_ws, size_t ws_size,
                              hipStream_t stream) {
    const float* q = (const float*)d_in[0];
    const float* k = (const float*)d_in[1];
    const float* v = (const float*)d_in[2];
    float* out = (float*)d_out;

    float*  scores = (float*)d_ws;
    ushort* attn   = (ushort*)((char*)d_ws + (size_t)B_ * 256 * 256 * 4);

    (void)hipMemsetAsync(d_ws, 0, (size_t)B_ * 256 * 256 * 4, stream);
    scores_kernel<<<1024, 512, 0, stream>>>(q, k, scores);
    softmax_kernel<<<2048, 256, 0, stream>>>(scores, attn);
    pv_kernel<<<2048, 256, 0, stream>>>(attn, v, out);
}